// Round 1
// baseline (107.560 us; speedup 1.0000x reference)
//
#include <hip/hip_runtime.h>

// VerifyConv2d backsubstitution, restructured as transposed convolution.
//
// Geometry (fixed): Cin=16, Cout=32, H=W=Oh=Ow=16, K=3, stride=1, pad=1.
// IN_DIM = 16*256 = 4096, OUT_DIM = 32*256 = 8192, N = 256 rows.
//
// new_uc[n, ci, ih, iw] = sum_{co,kh,kw} uc[n, co, ih+1-kh, iw+1-kw] * w[co,ci,kh,kw]
//   (terms with oh=ih+1-kh or ow=iw+1-kw outside [0,16) are dropped)
// new_uc_bias[n] = uc_bias[n] + sum_{co,p} uc[n, co*256+p] * bias[co]

#define IN_CH   16
#define OUT_CH  32
#define SPAT    256          // 16*16
#define IN_DIM  4096         // IN_CH * SPAT
#define OUT_DIM 8192         // OUT_CH * SPAT
#define NROWS   256

// transpose w[co][ci][kh][kw] -> wt[co][j=kh*3+kw][ci]  (4608 floats)
__global__ void prep_weight(const float* __restrict__ w, float* __restrict__ wt) {
    int t = threadIdx.x;
    for (int idx = t; idx < OUT_CH * 9 * IN_CH; idx += 256) {
        int co = idx / (9 * IN_CH);
        int r  = idx % (9 * IN_CH);
        int j  = r / IN_CH;
        int ci = r % IN_CH;
        wt[idx] = w[(co * IN_CH + ci) * 9 + j];
    }
}

__global__ __launch_bounds__(256) void backsub_kernel(
    const float* __restrict__ uc, const float* __restrict__ lc,
    const float* __restrict__ ucb, const float* __restrict__ lcb,
    const float* __restrict__ wt, const float* __restrict__ bias,
    float* __restrict__ out)
{
    __shared__ float row[OUT_DIM + 4];   // [OUT_DIM] is a zero sentinel for OOB taps
    __shared__ float red[4];

    const int t     = threadIdx.x;
    const int bid   = blockIdx.x;
    const int n     = bid & 255;
    const int which = bid >> 8;          // 0 = uc, 1 = lc

    const float* src = (which ? lc : uc) + (size_t)n * OUT_DIM;

    // ---- stage constraint row into LDS (coalesced float4) ----
    const float4* src4 = (const float4*)src;
    float4* row4 = (float4*)row;
    #pragma unroll
    for (int k = 0; k < 8; ++k)
        row4[k * 256 + t] = src4[k * 256 + t];
    if (t == 0) row[OUT_DIM] = 0.f;
    __syncthreads();

    // ---- fused bias backsubstitution: cb[n] + sum_co bias[co] * sum_p row[co,p] ----
    {
        float s = 0.f;
        #pragma unroll
        for (int k = 0; k < OUT_CH; ++k)
            s += bias[k] * row[k * SPAT + t];       // bias[k]: wave-uniform scalar load
        #pragma unroll
        for (int o = 32; o > 0; o >>= 1)
            s += __shfl_down(s, o, 64);
        if ((t & 63) == 0) red[t >> 6] = s;
    }
    __syncthreads();
    if (t == 0) {
        const float* cb = which ? lcb : ucb;
        out[2 * (size_t)NROWS * IN_DIM + which * NROWS + n] =
            cb[n] + red[0] + red[1] + red[2] + red[3];
    }

    // ---- main transposed conv: thread owns position (ih,iw), all 16 ci ----
    const int ih = t >> 4, iw = t & 15;

    int  pre[9];
    bool val[9];
    #pragma unroll
    for (int kh = 0; kh < 3; ++kh)
        #pragma unroll
        for (int kw = 0; kw < 3; ++kw) {
            int oh = ih + 1 - kh, ow = iw + 1 - kw;
            int j = kh * 3 + kw;
            val[j] = ((unsigned)oh < 16u) && ((unsigned)ow < 16u);
            pre[j] = oh * 16 + ow;
        }

    float acc[IN_CH];
    #pragma unroll
    for (int c = 0; c < IN_CH; ++c) acc[c] = 0.f;

    #pragma unroll 2
    for (int co = 0; co < OUT_CH; ++co) {
        const int cb = co * SPAT;
        float nb[9];
        #pragma unroll
        for (int j = 0; j < 9; ++j)
            nb[j] = row[val[j] ? (cb + pre[j]) : OUT_DIM];  // cndmask + ds_read

        const float4* w4 = (const float4*)(wt + co * 9 * IN_CH);
        #pragma unroll
        for (int j = 0; j < 9; ++j) {
            #pragma unroll
            for (int q = 0; q < 4; ++q) {
                float4 w = w4[j * 4 + q];    // wave-uniform -> s_load_dwordx4
                acc[q * 4 + 0] += w.x * nb[j];
                acc[q * 4 + 1] += w.y * nb[j];
                acc[q * 4 + 2] += w.z * nb[j];
                acc[q * 4 + 3] += w.w * nb[j];
            }
        }
    }

    // ---- write out (coalesced across lanes per ci) ----
    float* ob = out + (size_t)which * (NROWS * IN_DIM) + (size_t)n * IN_DIM;
    #pragma unroll
    for (int ci = 0; ci < IN_CH; ++ci)
        ob[ci * SPAT + t] = acc[ci];
}

extern "C" void kernel_launch(void* const* d_in, const int* in_sizes, int n_in,
                              void* d_out, int out_size, void* d_ws, size_t ws_size,
                              hipStream_t stream) {
    const float* uc   = (const float*)d_in[0];
    const float* lc   = (const float*)d_in[1];
    const float* ucb  = (const float*)d_in[2];
    const float* lcb  = (const float*)d_in[3];
    const float* w    = (const float*)d_in[4];
    const float* bias = (const float*)d_in[5];
    float* wt = (float*)d_ws;            // 4608 floats = 18 KB scratch

    prep_weight<<<1, 256, 0, stream>>>(w, wt);
    backsub_kernel<<<512, 256, 0, stream>>>(uc, lc, ucb, lcb, wt, bias, (float*)d_out);
}

// Round 2
// 86.955 us; speedup vs baseline: 1.2370x; 1.2370x over previous
//
#include <hip/hip_runtime.h>

// VerifyConv2d backsubstitution as per-row MFMA GEMM.
// Geometry: Cin=16, Cout=32, H=W=16, K=3, s=1, p=1. N=256 rows x {uc,lc}.
// Per block (one row r of uc or lc):
//   D[pos=256][ci=16] = sum_k A[pos][k] * W[k][ci],  k = j*32+co (j=kh*3+kw)
//   A[pos][j*32+co] = r[co][pos + (1-kh)*16 + (1-kw)]  (0 outside 16x16)
// fp32 realized as bf16 hi/lo split, 3 MFMA passes (hh + hl + lh).

#define NROWS   256
#define OUT_CH  32
#define IN_CH   16
#define SPAT    256
#define IN_DIM  4096
#define OUT_DIM 8192
#define CO_STRIDE 289     // 16 rows * 18 cols + 1 pad word (bank spread)

typedef __attribute__((ext_vector_type(8))) short    bf16x8;
typedef __attribute__((ext_vector_type(4))) float    f32x4;
typedef __attribute__((ext_vector_type(4))) unsigned u32x4;

__global__ __launch_bounds__(256) void backsub(
    const float* __restrict__ uc, const float* __restrict__ lc,
    const float* __restrict__ ucb, const float* __restrict__ lcb,
    const float* __restrict__ w, const float* __restrict__ bias,
    float* __restrict__ out)
{
    __shared__ float act[OUT_CH * CO_STRIDE];        // 36992 B, iw-halo layout
    __shared__ unsigned short bfr16[9 * 2 * 512];    // 18432 B, frag-ordered W hi/lo
    __shared__ float red[4];

    const int t     = threadIdx.x;
    const int n     = blockIdx.x & 255;
    const int which = blockIdx.x >> 8;               // 0 = uc, 1 = lc

    // ---- zero halo columns (cols 0 and 17 of every (co,row)) ----
    for (int i = t; i < OUT_CH * 16 * 2; i += 256) {
        int co = i >> 5, rr = i & 31, row = rr >> 1, side = rr & 1;
        act[co * CO_STRIDE + row * 18 + side * 17] = 0.f;
    }

    // ---- build B fragments: w[co][ci][j] -> bf16 hi/lo in MFMA frag order ----
    // frag value for (k=j*32+co, ci): lane = (co>>3)*16+ci, reg r = co&7
    #pragma unroll
    for (int i = 0; i < 18; ++i) {
        int v = t + i * 256;                 // 0..4607
        int j = v >> 9, rem = v & 511, co = rem >> 4, ci = rem & 15;
        float wv = w[(co * IN_CH + ci) * 9 + j];
        unsigned hb = __float_as_uint(wv) & 0xffff0000u;     // hi = truncate
        float    lf = wv - __uint_as_float(hb);              // exact remainder
        unsigned lb = __float_as_uint(lf) & 0xffff0000u;     // lo = truncate
        int lane = ((co >> 3) << 4) | ci;
        int r    = co & 7;
        bfr16[(2 * j + 0) * 512 + lane * 8 + r] = (unsigned short)(hb >> 16);
        bfr16[(2 * j + 1) * 512 + lane * 8 + r] = (unsigned short)(lb >> 16);
    }

    // ---- stage constraint row into halo LDS + fused bias dot ----
    const float*  srow = (which ? lc : uc) + (size_t)n * OUT_DIM;
    const float4* s4   = (const float4*)srow;
    float bs = 0.f;
    #pragma unroll
    for (int k = 0; k < 8; ++k) {
        float4 f = s4[t + k * 256];                  // coalesced
        int co  = (t >> 6) + 4 * k;
        bs += bias[co] * (f.x + f.y + f.z + f.w);
        int ih  = (t >> 2) & 15;
        int iw0 = (t & 3) * 4;
        int wd  = co * CO_STRIDE + ih * 18 + 1 + iw0;
        act[wd + 0] = f.x; act[wd + 1] = f.y; act[wd + 2] = f.z; act[wd + 3] = f.w;
    }
    #pragma unroll
    for (int o = 32; o > 0; o >>= 1) bs += __shfl_down(bs, o, 64);
    if ((t & 63) == 0) red[t >> 6] = bs;

    __syncthreads();

    if (t == 0) {
        const float* cb = which ? lcb : ucb;
        out[2 * (size_t)NROWS * IN_DIM + which * NROWS + n] =
            cb[n] + red[0] + red[1] + red[2] + red[3];
    }

    // ---- load B fragments to registers (broadcast reads, 16B aligned) ----
    const int l    = t & 63;
    const int wave = t >> 6;
    const int co_g = l >> 4;      // k-octet: co = co_g*8 + r
    const int il   = l & 15;      // A: pos-in-tile row; B/D: ci column

    bf16x8 Bh[9], Bl[9];
    #pragma unroll
    for (int j = 0; j < 9; ++j) {
        Bh[j] = *(const bf16x8*)&bfr16[(2 * j + 0) * 512 + l * 8];
        Bl[j] = *(const bf16x8*)&bfr16[(2 * j + 1) * 512 + l * 8];
    }

    // ---- main loop: wave owns pos [wave*64, wave*64+64), 4 M-tiles ----
    f32x4 acc[4];
    #pragma unroll
    for (int mt = 0; mt < 4; ++mt) acc[mt] = (f32x4){0.f, 0.f, 0.f, 0.f};

    #pragma unroll
    for (int mt = 0; mt < 4; ++mt) {
        const int ih = wave * 4 + mt;      // uniform per wave
        #pragma unroll
        for (int j = 0; j < 9; ++j) {
            const int kh = j / 3, kw = j % 3;
            const int ihn = ih + 1 - kh;
            if ((unsigned)ihn < 16u) {     // wave-uniform row-validity
                // gather 8 f32 (co = co_g*8 + q2) at same vaddr + imm offsets
                const float* p = &act[co_g * (8 * CO_STRIDE) + ihn * 18 + il + 2 - kw];
                u32x4 hv, lv;
                #pragma unroll
                for (int q = 0; q < 4; ++q) {
                    float a0 = p[(2 * q)     * CO_STRIDE];
                    float a1 = p[(2 * q + 1) * CO_STRIDE];
                    unsigned h0 = __float_as_uint(a0) & 0xffff0000u;
                    unsigned h1 = __float_as_uint(a1) & 0xffff0000u;
                    float l0 = a0 - __uint_as_float(h0);
                    float l1 = a1 - __uint_as_float(h1);
                    hv[q] = (h0 >> 16) | h1;
                    lv[q] = (__float_as_uint(l0) >> 16)
                          | (__float_as_uint(l1) & 0xffff0000u);
                }
                bf16x8 ah = __builtin_bit_cast(bf16x8, hv);
                bf16x8 al = __builtin_bit_cast(bf16x8, lv);
                acc[mt] = __builtin_amdgcn_mfma_f32_16x16x32_bf16(ah, Bh[j], acc[mt], 0, 0, 0);
                acc[mt] = __builtin_amdgcn_mfma_f32_16x16x32_bf16(ah, Bl[j], acc[mt], 0, 0, 0);
                acc[mt] = __builtin_amdgcn_mfma_f32_16x16x32_bf16(al, Bh[j], acc[mt], 0, 0, 0);
            }
        }
        // D: ci = il, pos = wave*64 + mt*16 + co_g*4 + reg (4 consecutive)
        float* ob = out + (size_t)which * (NROWS * IN_DIM) + (size_t)n * IN_DIM
                  + il * SPAT + wave * 64 + mt * 16 + co_g * 4;
        *(f32x4*)ob = acc[mt];
    }
}

extern "C" void kernel_launch(void* const* d_in, const int* in_sizes, int n_in,
                              void* d_out, int out_size, void* d_ws, size_t ws_size,
                              hipStream_t stream) {
    const float* uc   = (const float*)d_in[0];
    const float* lc   = (const float*)d_in[1];
    const float* ucb  = (const float*)d_in[2];
    const float* lcb  = (const float*)d_in[3];
    const float* w    = (const float*)d_in[4];
    const float* bias = (const float*)d_in[5];

    backsub<<<512, 256, 0, stream>>>(uc, lc, ucb, lcb, w, bias, (float*)d_out);
}

// Round 3
// 83.366 us; speedup vs baseline: 1.2902x; 1.0431x over previous
//
#include <hip/hip_runtime.h>

// VerifyConv2d backsubstitution as per-row MFMA GEMM, pre-packed bf16 hi/lo A.
// Geometry: Cin=16, Cout=32, H=W=16, K=3, s=1, p=1. N=256 rows x {uc,lc}.
// Per block (one row of uc or lc):
//   D[pos=256][ci=16] = sum_k A[pos][k] * W[k][ci],  k = j*32+co (j=kh*3+kw)
//   A[pos][j*32+co] = r[co][pos + (1-kh)*16 + (1-kw)]  (0 outside 16x16)
// fp32 realized as bf16 hi/lo split, 3 MFMA passes (hh + hl + lh).
// A is packed ONCE at staging into bf16 co-pair u32 arrays:
//   packA[(hl)*5760 + s*20 + (p ^ (((s>>3)&3)<<2))],  s = row*18 + halo_col
// so each (mt,j) A-octet is one aligned, bank-uniform ds_read_b128.

#define NROWS   256
#define OUT_CH  32
#define IN_CH   16
#define SPAT    256
#define IN_DIM  4096
#define OUT_DIM 8192
#define PSTR    20              // words per spatial slot (16 pairs + 4 pad)
#define PA_HALF (288 * PSTR)    // 5760 words per hi/lo plane

typedef __attribute__((ext_vector_type(8))) short    bf16x8;
typedef __attribute__((ext_vector_type(4))) float    f32x4;
typedef __attribute__((ext_vector_type(4))) unsigned u32x4;

__global__ __launch_bounds__(256) void backsub(
    const float* __restrict__ uc, const float* __restrict__ lc,
    const float* __restrict__ ucb, const float* __restrict__ lcb,
    const float* __restrict__ w, const float* __restrict__ bias,
    float* __restrict__ out)
{
    __shared__ unsigned packA[2 * PA_HALF];        // 46080 B
    __shared__ unsigned short bfr16[9 * 2 * 512];  // 18432 B
    __shared__ float red[4];

    const int t     = threadIdx.x;
    const int lane  = t & 63;
    const int wave  = t >> 6;
    const int n     = blockIdx.x & 255;
    const int which = blockIdx.x >> 8;             // 0 = uc, 1 = lc

    // ---- issue all row loads first (hide HBM latency under B-build) ----
    const float*  srow = (which ? lc : uc) + (size_t)n * OUT_DIM;
    const float4* s4   = (const float4*)srow;
    float4 av[4], bv[4];
    #pragma unroll
    for (int k = 0; k < 4; ++k) {
        int p = wave * 4 + k;                      // co-pair owned this iter
        av[k] = s4[(2 * p) * 64 + lane];           // co = 2p, coalesced
        bv[k] = s4[(2 * p + 1) * 64 + lane];       // co = 2p+1
    }

    // ---- build B fragments: w[co][ci][j] -> bf16 hi/lo in MFMA frag order ----
    #pragma unroll
    for (int i = 0; i < 18; ++i) {
        int v = t + i * 256;                       // 0..4607
        int j = v >> 9, rem = v & 511, co = rem >> 4, ci = rem & 15;
        float wv = w[(co * IN_CH + ci) * 9 + j];
        unsigned hb = __float_as_uint(wv) & 0xffff0000u;
        float    lf = wv - __uint_as_float(hb);
        unsigned lb = __float_as_uint(lf) & 0xffff0000u;
        int bl = ((co >> 3) << 4) | ci;
        int r  = co & 7;
        bfr16[(2 * j + 0) * 512 + bl * 8 + r] = (unsigned short)(hb >> 16);
        bfr16[(2 * j + 1) * 512 + bl * 8 + r] = (unsigned short)(lb >> 16);
    }

    // ---- zero halo cols (cols 0 and 17, all pairs, hi+lo) ----
    for (int i = t; i < 1024; i += 256) {
        int p = i & 15, sp = (i >> 4) & 31, a = i >> 9;
        int s = (sp >> 1) * 18 + (sp & 1) * 17;
        packA[a * PA_HALF + s * PSTR + p] = 0u;    // full 16-group: swizzle-free
    }

    // ---- pack staged row into bf16 hi/lo pairs + fused bias dot ----
    float bs = 0.f;
    const int row18 = lane >> 2;
    const int iw0   = (lane & 3) * 4;
    #pragma unroll
    for (int k = 0; k < 4; ++k) {
        int p = wave * 4 + k;
        float4 a = av[k], b = bv[k];
        bs += bias[2 * p]     * (a.x + a.y + a.z + a.w);
        bs += bias[2 * p + 1] * (b.x + b.y + b.z + b.w);
        const float* ae = (const float*)&a;
        const float* be = (const float*)&b;
        int s0 = row18 * 18 + 1 + iw0;
        #pragma unroll
        for (int i = 0; i < 4; ++i) {
            int s  = s0 + i;
            int pw = p ^ (((s >> 3) & 3) << 2);    // write-conflict swizzle
            unsigned ha = __float_as_uint(ae[i]) & 0xffff0000u;
            unsigned hb = __float_as_uint(be[i]) & 0xffff0000u;
            float la = ae[i] - __uint_as_float(ha);
            float lb = be[i] - __uint_as_float(hb);
            packA[s * PSTR + pw] = (ha >> 16) | hb;
            packA[PA_HALF + s * PSTR + pw] =
                (__float_as_uint(la) >> 16) | (__float_as_uint(lb) & 0xffff0000u);
        }
    }
    #pragma unroll
    for (int o = 32; o > 0; o >>= 1) bs += __shfl_down(bs, o, 64);
    if ((t & 63) == 0) red[wave] = bs;

    __syncthreads();

    if (t == 0) {
        const float* cb = which ? lcb : ucb;
        out[2 * (size_t)NROWS * IN_DIM + which * NROWS + n] =
            cb[n] + red[0] + red[1] + red[2] + red[3];
    }

    // ---- load B fragments (broadcast b128 reads) ----
    const int cg = lane >> 4;
    const int il = lane & 15;
    bf16x8 Bh[9], Bl[9];
    #pragma unroll
    for (int j = 0; j < 9; ++j) {
        Bh[j] = *(const bf16x8*)&bfr16[(2 * j + 0) * 512 + lane * 8];
        Bl[j] = *(const bf16x8*)&bfr16[(2 * j + 1) * 512 + lane * 8];
    }

    // ---- main loop: one aligned ds_read_b128 per A-octet, 3 MFMA per tap ----
    f32x4 acc[4];
    #pragma unroll
    for (int mt = 0; mt < 4; ++mt) acc[mt] = (f32x4){0.f, 0.f, 0.f, 0.f};

    #pragma unroll
    for (int mt = 0; mt < 4; ++mt) {
        const int ih = wave * 4 + mt;              // wave-uniform
        #pragma unroll
        for (int j = 0; j < 9; ++j) {
            const int kh = j / 3, kw = j % 3;
            const int ihn = ih + 1 - kh;
            if ((unsigned)ihn < 16u) {             // wave-uniform row validity
                int s    = ihn * 18 + il + 2 - kw;
                int cgx  = cg ^ ((s >> 3) & 3);    // read-side swizzle
                int word = s * PSTR + cgx * 4;     // 16B aligned
                u32x4 hv = *(const u32x4*)&packA[word];
                u32x4 lv = *(const u32x4*)&packA[PA_HALF + word];
                bf16x8 ah = __builtin_bit_cast(bf16x8, hv);
                bf16x8 al = __builtin_bit_cast(bf16x8, lv);
                acc[mt] = __builtin_amdgcn_mfma_f32_16x16x32_bf16(ah, Bh[j], acc[mt], 0, 0, 0);
                acc[mt] = __builtin_amdgcn_mfma_f32_16x16x32_bf16(ah, Bl[j], acc[mt], 0, 0, 0);
                acc[mt] = __builtin_amdgcn_mfma_f32_16x16x32_bf16(al, Bh[j], acc[mt], 0, 0, 0);
            }
        }
        // D: ci = il, pos = wave*64 + mt*16 + cg*4 + reg
        float* ob = out + (size_t)which * (NROWS * IN_DIM) + (size_t)n * IN_DIM
                  + il * SPAT + wave * 64 + mt * 16 + cg * 4;
        *(f32x4*)ob = acc[mt];
    }
}

extern "C" void kernel_launch(void* const* d_in, const int* in_sizes, int n_in,
                              void* d_out, int out_size, void* d_ws, size_t ws_size,
                              hipStream_t stream) {
    const float* uc   = (const float*)d_in[0];
    const float* lc   = (const float*)d_in[1];
    const float* ucb  = (const float*)d_in[2];
    const float* lcb  = (const float*)d_in[3];
    const float* w    = (const float*)d_in[4];
    const float* bias = (const float*)d_in[5];

    backsub<<<512, 256, 0, stream>>>(uc, lc, ucb, lcb, w, bias, (float*)d_out);
}